// Round 5
// baseline (500.535 us; speedup 1.0000x reference)
//
#include <hip/hip_runtime.h>

#define PH 14
#define PW 14
#define CC 512
#define IW 128
#define C4G (CC / 4)       // 128 float4 groups per pixel
#define SLICES 4
#define SG (C4G / SLICES)  // 32 float4 groups per channel slice
#define MAXW 32            // problem guarantees ROI span <= 32

typedef float f32x4 __attribute__((ext_vector_type(4)));

// Pre-pass: bin ROIs into 64 spatial cells (8x8 grid, Morton-ordered) and
// counting-sort into perm[] so ROIs near each other in the image are near
// each other in the schedule. One block, ~us.
__global__ __launch_bounds__(256) void roi_sort_kernel(
    const int* __restrict__ rois, int* __restrict__ perm, int n) {
  __shared__ int hist[64];
  __shared__ int base[64];
  __shared__ int cnt[64];
  int t = threadIdx.x;
  if (t < 64) { hist[t] = 0; cnt[t] = 0; }
  __syncthreads();
  for (int r = t; r < n; r += 256) {
    int xc = min((rois[4 * r + 0] + rois[4 * r + 2]) >> 5, 7);
    int yc = min((rois[4 * r + 1] + rois[4 * r + 3]) >> 5, 7);
    int key = (xc & 1) | ((yc & 1) << 1) | ((xc & 2) << 1) | ((yc & 2) << 2) |
              ((xc & 4) << 2) | ((yc & 4) << 3);
    atomicAdd(&hist[key], 1);
  }
  __syncthreads();
  if (t == 0) {
    int s = 0;
    for (int i = 0; i < 64; i++) { base[i] = s; s += hist[i]; }
  }
  __syncthreads();
  for (int r = t; r < n; r += 256) {
    int xc = min((rois[4 * r + 0] + rois[4 * r + 2]) >> 5, 7);
    int yc = min((rois[4 * r + 1] + rois[4 * r + 3]) >> 5, 7);
    int key = (xc & 1) | ((yc & 1) << 1) | ((xc & 2) << 1) | ((yc & 2) << 2) |
              ((xc & 4) << 2) | ((yc & 4) << 3);
    int pos = base[key] + atomicAdd(&cnt[key], 1);
    perm[pos] = r;
  }
}

// LDS-dedup kernel: block = (ROI, 128-channel slice). Walks the 14 output
// rows; ROI-local input rows are staged into a 2-slot LDS ring (slot = v&1).
// Ring-2 is sufficient: rb - rt <= 1 and row indices are nondecreasing, so
// at step j only rows {rb-1, rb} = {staged-1, staged} are ever read.
// Each input byte is read from global exactly ONCE per slice: total global
// reads ~0.55 GB vs 1.57 GB for the 4-corner direct scheme (2.8x dedup);
// corner re-reads move to LDS. 32 KB LDS/block -> ~5 blocks/CU.
__global__ __launch_bounds__(256) void roi_pool_lds(
    const float* __restrict__ img, const int* __restrict__ rois,
    const int* __restrict__ perm, float* __restrict__ out, int nroi8) {
  __shared__ f32x4 lds[2 * MAXW * SG];  // 2 slots x 32 px x 32 f4 = 32 KB

  int bid = blockIdx.x;
  int x   = bid & 7;        // target XCD (HW: XCD = blockIdx % 8)
  int seq = bid >> 3;       // dense sequence on this XCD
  int rg  = seq >> 2;       // ROI slot (spatially sorted)
  int sl  = seq & 3;        // channel slice 0..3
  int r   = perm[x * nroi8 + rg];

  int t  = threadIdx.x;
  int g  = t & 31;          // f4 group within slice
  int p0 = t >> 5;          // 0..7 (pixel stride for staging/compute)

  int x0 = rois[r * 4 + 0];
  int y0 = rois[r * 4 + 1];
  int in_w = rois[r * 4 + 2] - x0 + 1;
  int in_h = rois[r * 4 + 3] - y0 + 1;
  // Defensive clamp (spec guarantees <= 32); prevents LDS overrun on
  // malformed input without affecting valid inputs.
  in_w = min(in_w, MAXW);
  in_h = min(in_h, MAXW);

  // Match reference float op order: scale = in/out, then idx*scale.
  float scale_y = (float)in_h / (float)PH;
  float scale_x = (float)in_w / (float)PW;

  const f32x4* img4 = (const f32x4*)img;
  f32x4* out4 = (f32x4*)out;

  int staged = -1;
  for (int j = 0; j < PH; ++j) {
    float syf = (float)j * scale_y;
    int yt = (int)floorf(syf);
    int rbl = min(yt + 1, in_h - 1);
    float wy = syf - (float)yt;

    if (rbl > staged) {  // uniform across block
      __syncthreads();   // previous compute done before slot overwrite
      for (int v = staged + 1; v <= rbl; ++v) {
        const f32x4* src =
            img4 + ((size_t)(y0 + v) * IW + x0) * C4G + sl * SG + g;
        f32x4* dst = lds + (size_t)(v & 1) * (MAXW * SG) + g;
        // register-stage first (4 loads in flight), then LDS writes
        f32x4 t0, t1, t2, t3;
        int p1 = p0 + 8, p2 = p0 + 16, p3 = p0 + 24;
        if (p0 < in_w) t0 = src[(size_t)p0 * C4G];
        if (p1 < in_w) t1 = src[(size_t)p1 * C4G];
        if (p2 < in_w) t2 = src[(size_t)p2 * C4G];
        if (p3 < in_w) t3 = src[(size_t)p3 * C4G];
        if (p0 < in_w) dst[p0 * SG] = t0;
        if (p1 < in_w) dst[p1 * SG] = t1;
        if (p2 < in_w) dst[p2 * SG] = t2;
        if (p3 < in_w) dst[p3 * SG] = t3;
      }
      staged = rbl;
      __syncthreads();   // staged rows visible before compute
    }

    const f32x4* lt = lds + (size_t)(yt & 1) * (MAXW * SG);
    const f32x4* lb = lds + (size_t)(rbl & 1) * (MAXW * SG);
    f32x4 wyv = wy;

#pragma unroll
    for (int h = 0; h < 2; ++h) {
      int idx = t + h * 256;
      if (idx < PW * SG) {  // 448 items: (px, g)
        int px = idx >> 5;
        int gg = idx & 31;
        float sxf = (float)px * scale_x;
        int xt = (int)floorf(sxf);
        int xr = min(xt + 1, in_w - 1);
        float wx = sxf - (float)xt;

        f32x4 v00 = lt[xt * SG + gg];
        f32x4 v01 = lt[xr * SG + gg];
        f32x4 v10 = lb[xt * SG + gg];
        f32x4 v11 = lb[xr * SG + gg];

        f32x4 wxv = wx;
        f32x4 top = v00 + wxv * (v01 - v00);
        f32x4 bot = v10 + wxv * (v11 - v10);
        f32x4 res = top + wyv * (bot - top);

        size_t pid = (size_t)r * (PH * PW) + j * PW + px;
        __builtin_nontemporal_store(res, out4 + pid * C4G + sl * SG + gg);
      }
    }
  }
}

// Fallback (generic N / no workspace): direct 4-corner kernel, one wave per
// output pixel, 2 f4 groups per lane.
__global__ __launch_bounds__(256) void roi_pool_flat(
    const float* __restrict__ img, const int* __restrict__ rois,
    float* __restrict__ out, int npix) {
  int wid = blockIdx.x * 4 + (threadIdx.x >> 6);
  if (wid >= npix) return;
  int pid = __builtin_amdgcn_readfirstlane(wid);
  int lane = threadIdx.x & 63;

  int px = pid % PW;
  int tmp = pid / PW;
  int py = tmp % PH;
  int n = tmp / PH;

  int x0 = rois[n * 4 + 0];
  int y0 = rois[n * 4 + 1];
  int in_w = rois[n * 4 + 2] - x0 + 1;
  int in_h = rois[n * 4 + 3] - y0 + 1;

  float scale_y = (float)in_h / (float)PH;
  float scale_x = (float)in_w / (float)PW;
  float sy = (float)py * scale_y;
  float sx = (float)px * scale_x;
  int yt = (int)floorf(sy);
  int xt = (int)floorf(sx);
  int yb = min(yt + 1, in_h - 1);
  int xr = min(xt + 1, in_w - 1);
  float wy = sy - (float)yt;
  float wx = sx - (float)xt;

  int rt = y0 + yt, rb = y0 + yb;
  int cl = x0 + xt, cr = x0 + xr;

  const f32x4* imgv = (const f32x4*)img;
  const f32x4* p00 = imgv + (size_t)(rt * IW + cl) * C4G + lane;
  const f32x4* p01 = imgv + (size_t)(rt * IW + cr) * C4G + lane;
  const f32x4* p10 = imgv + (size_t)(rb * IW + cl) * C4G + lane;
  const f32x4* p11 = imgv + (size_t)(rb * IW + cr) * C4G + lane;

  f32x4 a00 = p00[0], b00 = p00[64];
  f32x4 a01 = p01[0], b01 = p01[64];
  f32x4 a10 = p10[0], b10 = p10[64];
  f32x4 a11 = p11[0], b11 = p11[64];

  f32x4 wxv = wx, wyv = wy;
  f32x4 atop = a00 + wxv * (a01 - a00);
  f32x4 abot = a10 + wxv * (a11 - a10);
  f32x4 ra = atop + wyv * (abot - atop);
  f32x4 btop = b00 + wxv * (b01 - b00);
  f32x4 bbot = b10 + wxv * (b11 - b10);
  f32x4 rbv = btop + wyv * (bbot - btop);

  f32x4* outv = (f32x4*)out + (size_t)pid * C4G + lane;
  __builtin_nontemporal_store(ra, outv);
  __builtin_nontemporal_store(rbv, outv + 64);
}

extern "C" void kernel_launch(void* const* d_in, const int* in_sizes, int n_in,
                              void* d_out, int out_size, void* d_ws, size_t ws_size,
                              hipStream_t stream) {
  const float* img = (const float*)d_in[0];
  const int* rois = (const int*)d_in[1];
  float* out = (float*)d_out;

  int N = in_sizes[1] / 4;   // rois is [N,4]
  int* perm = (int*)d_ws;

  bool lds_path = (N > 0) && ((N % 8) == 0) && (d_ws != nullptr) &&
                  (ws_size >= (size_t)N * sizeof(int));
  if (lds_path) {
    roi_sort_kernel<<<1, 256, 0, stream>>>(rois, perm, N);
    int blocks = N * SLICES;  // (ROI, channel-slice); % 8 == 0 by N % 8 == 0
    roi_pool_lds<<<blocks, 256, 0, stream>>>(img, rois, perm, out, N / 8);
  } else {
    int npix = N * PH * PW;
    int blocks = (npix + 3) / 4;
    roi_pool_flat<<<blocks, 256, 0, stream>>>(img, rois, out, npix);
  }
}

// Round 6
// 436.712 us; speedup vs baseline: 1.1461x; 1.1461x over previous
//
#include <hip/hip_runtime.h>

#define PH 14
#define PW 14
#define CC 512
#define IW 128
#define C4G (CC / 4)  // 128 float4 groups per pixel

typedef float f32x4 __attribute__((ext_vector_type(4)));

// Pre-pass: bin ROIs into 64 spatial cells (8x8 grid, Morton-ordered) and
// counting-sort into perm[] so ROIs near each other in the image are near
// each other in the schedule. One block, ~us.
__global__ __launch_bounds__(256) void roi_sort_kernel(
    const int* __restrict__ rois, int* __restrict__ perm, int n) {
  __shared__ int hist[64];
  __shared__ int base[64];
  __shared__ int cnt[64];
  int t = threadIdx.x;
  if (t < 64) { hist[t] = 0; cnt[t] = 0; }
  __syncthreads();
  for (int r = t; r < n; r += 256) {
    int xc = min((rois[4 * r + 0] + rois[4 * r + 2]) >> 5, 7);
    int yc = min((rois[4 * r + 1] + rois[4 * r + 3]) >> 5, 7);
    int key = (xc & 1) | ((yc & 1) << 1) | ((xc & 2) << 1) | ((yc & 2) << 2) |
              ((xc & 4) << 2) | ((yc & 4) << 3);
    atomicAdd(&hist[key], 1);
  }
  __syncthreads();
  if (t == 0) {
    int s = 0;
    for (int i = 0; i < 64; i++) { base[i] = s; s += hist[i]; }
  }
  __syncthreads();
  for (int r = t; r < n; r += 256) {
    int xc = min((rois[4 * r + 0] + rois[4 * r + 2]) >> 5, 7);
    int yc = min((rois[4 * r + 1] + rois[4 * r + 3]) >> 5, 7);
    int key = (xc & 1) | ((yc & 1) << 1) | ((xc & 2) << 1) | ((yc & 2) << 2) |
              ((xc & 4) << 2) | ((yc & 4) << 3);
    int pos = base[key] + atomicAdd(&cnt[key], 1);
    perm[pos] = r;
  }
}

// Row-block kernel: block = (ROI, output row j), 14 waves = the 14 pixels of
// that row. Wave w computes pixel (j, w): identical math and loads to the
// proven direct kernel — no LDS, no barriers, fully independent waves.
// Why this geometry: all 14 pixels of a row read the SAME two input rows
// (rt, rb) and heavily overlapping columns (~30 distinct 1KB line-groups vs
// 56 issued). Co-locating them on one CU lets the L1/MSHR merge duplicate
// line requests so they count once toward the per-CU outstanding-request
// ceiling and L2 bandwidth — dedup with zero synchronization cost.
__global__ __launch_bounds__(896) void roi_pool_row(
    const float* __restrict__ img, const int* __restrict__ rois,
    const int* __restrict__ perm, float* __restrict__ out, int nroi8) {
  int bid = blockIdx.x;
  int x   = bid & 7;        // target XCD (HW: XCD = blockIdx % 8)
  int seq = bid >> 3;       // dense sequence on this XCD
  int rg  = seq / PH;       // ROI slot (spatially sorted)
  int j   = seq % PH;       // output row
  int r   = perm[x * nroi8 + rg];

  int px   = threadIdx.x >> 6;  // wave index = pixel within row (0..13)
  int lane = threadIdx.x & 63;
  int pid  = __builtin_amdgcn_readfirstlane(r * (PH * PW) + j * PW + px);

  int x0 = rois[r * 4 + 0];
  int y0 = rois[r * 4 + 1];
  int in_w = rois[r * 4 + 2] - x0 + 1;
  int in_h = rois[r * 4 + 3] - y0 + 1;

  // Match reference float op order exactly: scale = in/out, then idx*scale.
  float scale_y = (float)in_h / (float)PH;
  float scale_x = (float)in_w / (float)PW;
  float sy = (float)j * scale_y;
  float sx = (float)px * scale_x;
  int yt = (int)floorf(sy);
  int xt = (int)floorf(sx);
  int yb = min(yt + 1, in_h - 1);
  int xr = min(xt + 1, in_w - 1);
  float wy = sy - (float)yt;
  float wx = sx - (float)xt;

  int rt = y0 + yt, rb = y0 + yb;
  int cl = x0 + xt, cr = x0 + xr;

  const f32x4* __restrict__ imgv = (const f32x4*)img;
  const f32x4* p00 = imgv + (size_t)(rt * IW + cl) * C4G + lane;
  const f32x4* p01 = imgv + (size_t)(rt * IW + cr) * C4G + lane;
  const f32x4* p10 = imgv + (size_t)(rb * IW + cl) * C4G + lane;
  const f32x4* p11 = imgv + (size_t)(rb * IW + cr) * C4G + lane;

  // 8 loads in flight per wave
  f32x4 a00 = p00[0], b00 = p00[64];
  f32x4 a01 = p01[0], b01 = p01[64];
  f32x4 a10 = p10[0], b10 = p10[64];
  f32x4 a11 = p11[0], b11 = p11[64];

  f32x4 wxv = wx, wyv = wy;

  f32x4 atop = a00 + wxv * (a01 - a00);
  f32x4 abot = a10 + wxv * (a11 - a10);
  f32x4 ra = atop + wyv * (abot - atop);

  f32x4 btop = b00 + wxv * (b01 - b00);
  f32x4 bbot = b10 + wxv * (b11 - b10);
  f32x4 rbv = btop + wyv * (bbot - btop);

  // Output is never re-read: non-temporal stores keep the 401 MB write
  // stream from evicting image lines out of L2.
  f32x4* outv = (f32x4*)out + (size_t)pid * C4G + lane;
  __builtin_nontemporal_store(ra, outv);
  __builtin_nontemporal_store(rbv, outv + 64);
}

// Fallback (generic N / no workspace): direct 4-corner kernel, one wave per
// output pixel, 2 f4 groups per lane.
__global__ __launch_bounds__(256) void roi_pool_flat(
    const float* __restrict__ img, const int* __restrict__ rois,
    float* __restrict__ out, int npix) {
  int wid = blockIdx.x * 4 + (threadIdx.x >> 6);
  if (wid >= npix) return;
  int pid = __builtin_amdgcn_readfirstlane(wid);
  int lane = threadIdx.x & 63;

  int px = pid % PW;
  int tmp = pid / PW;
  int py = tmp % PH;
  int n = tmp / PH;

  int x0 = rois[n * 4 + 0];
  int y0 = rois[n * 4 + 1];
  int in_w = rois[n * 4 + 2] - x0 + 1;
  int in_h = rois[n * 4 + 3] - y0 + 1;

  float scale_y = (float)in_h / (float)PH;
  float scale_x = (float)in_w / (float)PW;
  float sy = (float)py * scale_y;
  float sx = (float)px * scale_x;
  int yt = (int)floorf(sy);
  int xt = (int)floorf(sx);
  int yb = min(yt + 1, in_h - 1);
  int xr = min(xt + 1, in_w - 1);
  float wy = sy - (float)yt;
  float wx = sx - (float)xt;

  int rt = y0 + yt, rb = y0 + yb;
  int cl = x0 + xt, cr = x0 + xr;

  const f32x4* imgv = (const f32x4*)img;
  const f32x4* p00 = imgv + (size_t)(rt * IW + cl) * C4G + lane;
  const f32x4* p01 = imgv + (size_t)(rt * IW + cr) * C4G + lane;
  const f32x4* p10 = imgv + (size_t)(rb * IW + cl) * C4G + lane;
  const f32x4* p11 = imgv + (size_t)(rb * IW + cr) * C4G + lane;

  f32x4 a00 = p00[0], b00 = p00[64];
  f32x4 a01 = p01[0], b01 = p01[64];
  f32x4 a10 = p10[0], b10 = p10[64];
  f32x4 a11 = p11[0], b11 = p11[64];

  f32x4 wxv = wx, wyv = wy;
  f32x4 atop = a00 + wxv * (a01 - a00);
  f32x4 abot = a10 + wxv * (a11 - a10);
  f32x4 ra = atop + wyv * (abot - atop);
  f32x4 btop = b00 + wxv * (b01 - b00);
  f32x4 bbot = b10 + wxv * (b11 - b10);
  f32x4 rbv = btop + wyv * (bbot - btop);

  f32x4* outv = (f32x4*)out + (size_t)pid * C4G + lane;
  __builtin_nontemporal_store(ra, outv);
  __builtin_nontemporal_store(rbv, outv + 64);
}

extern "C" void kernel_launch(void* const* d_in, const int* in_sizes, int n_in,
                              void* d_out, int out_size, void* d_ws, size_t ws_size,
                              hipStream_t stream) {
  const float* img = (const float*)d_in[0];
  const int* rois = (const int*)d_in[1];
  float* out = (float*)d_out;

  int N = in_sizes[1] / 4;   // rois is [N,4]
  int* perm = (int*)d_ws;

  bool row_path = (N > 0) && ((N % 8) == 0) && (d_ws != nullptr) &&
                  (ws_size >= (size_t)N * sizeof(int));
  if (row_path) {
    roi_sort_kernel<<<1, 256, 0, stream>>>(rois, perm, N);
    // block = (ROI, output row): N*14 blocks, 896 threads (14 waves = 14 px)
    int blocks = N * PH;  // % 8 == 0 since N % 8 == 0
    roi_pool_row<<<blocks, PH * 64, 0, stream>>>(img, rois, perm, out, N / 8);
  } else {
    int npix = N * PH * PW;
    int blocks = (npix + 3) / 4;
    roi_pool_flat<<<blocks, 256, 0, stream>>>(img, rois, out, npix);
  }
}